// Round 12
// baseline (193.310 us; speedup 1.0000x reference)
//
#include <hip/hip_runtime.h>
#include <hip/hip_bf16.h>

#define B_   8
#define C_   256
#define CQ_  32
#define N_   4096
#define OC_  320   // stacked output channels: q 0..31 | k 32..63 | v 64..319

typedef __bf16 bf16;
typedef __attribute__((ext_vector_type(8))) __bf16 bf16x8;
typedef __attribute__((ext_vector_type(4))) __bf16 bf16x4;
typedef __attribute__((ext_vector_type(4))) float f32x4;

#define LOG2E 1.4426950408889634f

// ws layout (bf16 element offsets):
//   qT [B][N][CQ] | kT [B][N][CQ] | vb [B][C][N] | Wb [320][256] | xT [B][N][C]
//   then fp32 bias[320] at byte offset BIAS_BYTE.
#define QT_OFF ((size_t)0)
#define KT_OFF ((size_t)B_*N_*CQ_)
#define VB_OFF ((size_t)2*B_*N_*CQ_)
#define WB_OFF (VB_OFF + (size_t)B_*C_*N_)
#define XT_OFF (WB_OFF + (size_t)OC_*C_)
#define WS_END_BF16 (XT_OFF + (size_t)B_*N_*C_)
#define BIAS_BYTE (WS_END_BF16*2)
#define WS_BYTES (BIAS_BYTE + OC_*4)

// exp2 via builtin (compiler-visible TRANS op; hazards handled).
__device__ inline float exp2_hw(float x) {
  return __builtin_amdgcn_exp2f(x);
}

// ---------------------------------------------------------------------------
// prep_w: stack Wq|Wk|Wv -> bf16 Wb[320][256], biases -> fp32[320].
// ---------------------------------------------------------------------------
__global__ __launch_bounds__(256) void prep_w(
    const float* __restrict__ Wq, const float* __restrict__ bq,
    const float* __restrict__ Wk, const float* __restrict__ bk,
    const float* __restrict__ Wv, const float* __restrict__ bv,
    bf16* __restrict__ ws)
{
  const int idx = blockIdx.x*256 + threadIdx.x;      // 0..81919
  const int o = idx >> 8, c = idx & 255;
  const float v = (o < 32) ? Wq[o*C_ + c]
                : (o < 64) ? Wk[(o-32)*C_ + c]
                           : Wv[(o-64)*C_ + c];
  ws[WB_OFF + idx] = (bf16)v;
  if (idx < OC_) {
    const float bb = (idx < 32) ? bq[idx] : (idx < 64) ? bk[idx-32] : bv[idx-64];
    ((float*)((char*)ws + BIAS_BYTE))[idx] = bb;
  }
}

// ---------------------------------------------------------------------------
// prep_x: x fp32 [B][C][N] -> bf16 xT [B][N][C] (B-frag layout, contiguous c).
// ---------------------------------------------------------------------------
__global__ __launch_bounds__(256) void prep_x(
    const float* __restrict__ x, bf16* __restrict__ ws)
{
  const int b  = blockIdx.z;
  const int n  = blockIdx.x*64 + (threadIdx.x & 63);
  const int c0 = blockIdx.y*32 + (threadIdx.x >> 6)*8;
  const float* xp = x + ((size_t)b*C_ + c0)*N_ + n;
  bf16x8 pk;
  #pragma unroll
  for (int j = 0; j < 8; ++j) pk[j] = (bf16)xp[(size_t)j*N_];
  *(bf16x8*)(ws + XT_OFF + ((size_t)b*N_ + n)*C_ + c0) = pk;
}

// ---------------------------------------------------------------------------
// qkv_mfma: D[o][n] = sum_c Wb[o][c] xT[n][c] + bias[o]. Per block: 320 o x
// 64 n. 4 waves; wave w owns 5 o-tiles. K=256 in 8 MFMA steps, no LDS.
// q outputs pre-scaled by LOG2E so attention uses raw 2^x.
// ---------------------------------------------------------------------------
__global__ __launch_bounds__(256) void qkv_mfma(
    const bf16* __restrict__ wsc, bf16* __restrict__ ws)
{
  const int b   = blockIdx.y;
  const int n0  = blockIdx.x * 64;
  const int tid = threadIdx.x, lane = tid & 63;
  const int w   = __builtin_amdgcn_readfirstlane(tid >> 6);
  const int lm  = lane & 15, g = lane >> 4;
  const int obase = w*80;

  const bf16*  Wb   = wsc + WB_OFF;
  const bf16*  xT   = wsc + XT_OFF + (size_t)b*N_*C_;
  const float* bias = (const float*)((const char*)wsc + BIAS_BYTE);

  f32x4 acc[5][4];
  #pragma unroll
  for (int ot = 0; ot < 5; ++ot)
    #pragma unroll
    for (int nt = 0; nt < 4; ++nt)
      acc[ot][nt] = (f32x4){0.f, 0.f, 0.f, 0.f};

  for (int kk = 0; kk < 8; ++kk) {
    bf16x8 wa[5], xf[4];
    #pragma unroll
    for (int ot = 0; ot < 5; ++ot)
      wa[ot] = *(const bf16x8*)(Wb + (size_t)(obase + ot*16 + lm)*C_ + kk*32 + g*8);
    #pragma unroll
    for (int nt = 0; nt < 4; ++nt)
      xf[nt] = *(const bf16x8*)(xT + (size_t)(n0 + nt*16 + lm)*C_ + kk*32 + g*8);
    #pragma unroll
    for (int ot = 0; ot < 5; ++ot)
      #pragma unroll
      for (int nt = 0; nt < 4; ++nt)
        acc[ot][nt] = __builtin_amdgcn_mfma_f32_16x16x32_bf16(
                        wa[ot], xf[nt], acc[ot][nt], 0, 0, 0);
  }

  float bv4[5][4];
  #pragma unroll
  for (int ot = 0; ot < 5; ++ot)
    #pragma unroll
    for (int r = 0; r < 4; ++r)
      bv4[ot][r] = bias[obase + ot*16 + g*4 + r];

  bf16* qT = ws + QT_OFF + (size_t)b*N_*CQ_;
  bf16* kT = ws + KT_OFF + (size_t)b*N_*CQ_;
  bf16* vb = ws + VB_OFF + (size_t)b*C_*N_;

  #pragma unroll
  for (int ot = 0; ot < 5; ++ot) {
    const int O = obase + ot*16;
    #pragma unroll
    for (int nt = 0; nt < 4; ++nt) {
      const int n = n0 + nt*16 + lm;
      if (O < 32) {
        bf16x4 pk;   // q: fold log2(e) so attn exp is a bare v_exp_f32
        #pragma unroll
        for (int r = 0; r < 4; ++r)
          pk[r] = (bf16)((acc[ot][nt][r] + bv4[ot][r]) * LOG2E);
        *(bf16x4*)(qT + (size_t)n*CQ_ + O + g*4) = pk;
      } else if (O < 64) {
        bf16x4 pk;
        #pragma unroll
        for (int r = 0; r < 4; ++r) pk[r] = (bf16)(acc[ot][nt][r] + bv4[ot][r]);
        *(bf16x4*)(kT + (size_t)n*CQ_ + (O - 32) + g*4) = pk;
      } else {
        #pragma unroll
        for (int r = 0; r < 4; ++r)
          vb[(size_t)(O - 64 + g*4 + r)*N_ + n] = (bf16)(acc[ot][nt][r] + bv4[ot][r]);
      }
    }
  }
}

// ---------------------------------------------------------------------------
// attn_kernel v7: barrier-free, LDS-free, fully wave-independent.
// 512 blocks x 4 waves. b = bid&7 (XCD-affine), m0 = (bid>>3)*64.
// Wave w owns c-slice [64w, 64w+64); every wave computes the FULL S slab for
// its m-range itself (QK^T duplicated x4 per block -- the price of removing
// the cross-wave LDS-P + barrier convoy that pinned all variants at ~150us).
//
// Key trick: QK^T A-operand loaded with ROW-PERMUTED q: A row a holds
// q row perm(a) = 8*(a>>2) + (a&3)  (frag1: +4). Then the D-frag at lane
// (g,lm) holds S[n_local = 8g + {0..3}] (frag0) / 8g+{4..7} (frag1) for
// column lm -- after exp2 + bf16 pack this IS the PV B-frag (k=g*8+j,
// col=lm). Softmax->PV handoff is 4 register packs: no LDS, no barrier,
// no shuffle. Denominator: each wave owns the full colsum (2 shfl_xor at
// the end); no cross-wave reduction.
// ---------------------------------------------------------------------------
__global__ __launch_bounds__(256, 2) void attn_kernel(
    const bf16* __restrict__ ws, const float* __restrict__ x,
    const float* __restrict__ gamma, float* __restrict__ out)
{
  const int bid  = blockIdx.x;
  const int b    = bid & 7;
  const int m0   = (bid >> 3) << 6;
  const int tid  = threadIdx.x;
  const int lane = tid & 63;
  const int w    = __builtin_amdgcn_readfirstlane(tid >> 6);   // 0..3
  const int lm   = lane & 15;
  const int g    = lane >> 4;

  const bf16* qT = ws + QT_OFF + (size_t)b*N_*CQ_;
  const bf16* kT = ws + KT_OFF + (size_t)b*N_*CQ_;
  const bf16* vb = ws + VB_OFF + (size_t)b*C_*N_;

  // k B-frags for the block's 64 m-columns (constant over loop)
  bf16x8 kb[4];
  #pragma unroll
  for (int ms = 0; ms < 4; ++ms)
    kb[ms] = *(const bf16x8*)(kT + (size_t)(m0 + ms*16 + lm)*CQ_ + g*8);

  f32x4 acc[4][4];                 // [c-subtile][m-subtile]
  #pragma unroll
  for (int cs = 0; cs < 4; ++cs)
    #pragma unroll
    for (int ms = 0; ms < 4; ++ms)
      acc[cs][ms] = (f32x4){0.f, 0.f, 0.f, 0.f};
  float colsum[4] = {0.f, 0.f, 0.f, 0.f};

  const int c0 = w*64;
  const f32x4 zero4 = (f32x4){0.f, 0.f, 0.f, 0.f};

  // per-lane base pointers
  //   q row-permuted: row = 8*(lm>>2) + (lm&3)  (+4 for frag1), k = g*8..
  const bf16* qpb = qT + (size_t)(8*(lm >> 2) + (lm & 3))*CQ_ + g*8;
  const bf16* vpb = vb + (size_t)(c0 + lm)*N_ + g*8;

  for (int t = 0; t < 128; ++t) {
    const size_t n0 = (size_t)t * 32;

    // ---- loads: 2 permuted q-frags + 4 v A-frags (all independent) ----
    bf16x8 qf0 = *(const bf16x8*)(qpb + n0*CQ_);
    bf16x8 qf1 = *(const bf16x8*)(qpb + n0*CQ_ + 4*CQ_);
    bf16x8 vf[4];
    #pragma unroll
    for (int cs = 0; cs < 4; ++cs)
      vf[cs] = *(const bf16x8*)(vpb + (size_t)cs*16*N_ + n0);

    // ---- QK^T: S[32 n (permuted layout)][64 m] ----
    f32x4 s0[4], s1[4];
    #pragma unroll
    for (int ms = 0; ms < 4; ++ms) {
      s0[ms] = __builtin_amdgcn_mfma_f32_16x16x32_bf16(qf0, kb[ms], zero4, 0, 0, 0);
      s1[ms] = __builtin_amdgcn_mfma_f32_16x16x32_bf16(qf1, kb[ms], zero4, 0, 0, 0);
    }

    // ---- exp2 -> in-register PV B-frags (zero LDS/shuffle handoff) ----
    bf16x8 pfrag[4];
    #pragma unroll
    for (int ms = 0; ms < 4; ++ms) {
      float e0 = exp2_hw(s0[ms][0]);
      float e1 = exp2_hw(s0[ms][1]);
      float e2 = exp2_hw(s0[ms][2]);
      float e3 = exp2_hw(s0[ms][3]);
      float e4 = exp2_hw(s1[ms][0]);
      float e5 = exp2_hw(s1[ms][1]);
      float e6 = exp2_hw(s1[ms][2]);
      float e7 = exp2_hw(s1[ms][3]);
      colsum[ms] += ((e0 + e1) + (e2 + e3)) + ((e4 + e5) + (e6 + e7));
      bf16x8 pf;
      pf[0] = (bf16)e0; pf[1] = (bf16)e1; pf[2] = (bf16)e2; pf[3] = (bf16)e3;
      pf[4] = (bf16)e4; pf[5] = (bf16)e5; pf[6] = (bf16)e6; pf[7] = (bf16)e7;
      pfrag[ms] = pf;
    }

    // ---- PV: acc[cs][ms] += v[c-slice][n-chunk] @ P[n-chunk][m] ----
    #pragma unroll
    for (int cs = 0; cs < 4; ++cs)
      #pragma unroll
      for (int ms = 0; ms < 4; ++ms)
        acc[cs][ms] = __builtin_amdgcn_mfma_f32_16x16x32_bf16(
                        vf[cs], pfrag[ms], acc[cs][ms], 0, 0, 0);
  }

  // ---- denominators: this wave owns the full sum; reduce over g-groups ----
  #pragma unroll
  for (int ms = 0; ms < 4; ++ms) {
    colsum[ms] += __shfl_xor(colsum[ms], 16, 64);
    colsum[ms] += __shfl_xor(colsum[ms], 32, 64);
  }

  // ---- epilogue: out = gamma*O/denom + x ----
  const float gam = gamma[0];
  float inv[4];
  #pragma unroll
  for (int ms = 0; ms < 4; ++ms) inv[ms] = gam / colsum[ms];

  #pragma unroll
  for (int cs = 0; cs < 4; ++cs)
    #pragma unroll
    for (int ms = 0; ms < 4; ++ms)
      #pragma unroll
      for (int r = 0; r < 4; ++r) {
        const int c = c0 + cs*16 + g*4 + r;
        const int m = m0 + 16*ms + lm;
        const size_t idx = ((size_t)b*C_ + c)*N_ + m;
        out[idx] = acc[cs][ms][r] * inv[ms] + x[idx];
      }
}

extern "C" void kernel_launch(void* const* d_in, const int* in_sizes, int n_in,
                              void* d_out, int out_size, void* d_ws, size_t ws_size,
                              hipStream_t stream) {
  const float* x     = (const float*)d_in[0];
  const float* Wq    = (const float*)d_in[1];
  const float* bq    = (const float*)d_in[2];
  const float* Wk    = (const float*)d_in[3];
  const float* bk    = (const float*)d_in[4];
  const float* Wv    = (const float*)d_in[5];
  const float* bv    = (const float*)d_in[6];
  const float* gamma = (const float*)d_in[7];
  float* out = (float*)d_out;
  bf16* ws   = (bf16*)d_ws;

  if (ws_size < WS_BYTES) return;   // ~37.9 MB scratch

  prep_w<<<320, 256, 0, stream>>>(Wq, bq, Wk, bk, Wv, bv, ws);
  prep_x<<<dim3(64, 8, 8), 256, 0, stream>>>(x, ws);
  qkv_mfma<<<dim3(64, 8), 256, 0, stream>>>(ws, ws);
  attn_kernel<<<512, 256, 0, stream>>>(ws, x, gamma, out);
}